// Round 4
// baseline (284.823 us; speedup 1.0000x reference)
//
#include <hip/hip_runtime.h>
#include <math.h>

#define TOKENS 16384
#define DMODEL 2048
#define NEXP   64
#define TOPK   8
#define BM     64
#define BK     32
#define BKP    36   // row stride: 36 floats = 144 B -> 16B-aligned rows, stride-36
                    // b128 reads are 2-way bank-aliased (free), b128 staging
                    // writes tile all 32 banks (zero conflict phases)

// Kernel 1: partial logits. part[kc][t][e] = sum_{k in chunk kc} x[t][k]*W[e][k]
// 64 tokens x 64 experts per 256-thread block, 4x4 register tile, grid.y = ksplit.
// Row-major LDS tiles (b128 staging writes), software-pipelined: tile t+1's
// global loads are issued before tile t's compute so HBM latency overlaps the
// ~1000-cycle FMA phase instead of being exposed at the barrier.
// fp32 FMA chunks of 16 flushed into fp64 accumulators (~2e-7 total rounding:
// numpy-grade top-k ordering at ~15% VALU overhead).
__global__ __launch_bounds__(256) void router_gemm(
    const float* __restrict__ x, const float* __restrict__ W,
    float* __restrict__ part, int kchunk)
{
    __shared__ float xs[BM][BKP];    // xs[token][k]
    __shared__ float ws[NEXP][BKP];  // ws[expert][k]

    const int tid = threadIdx.x;
    const int kq  = tid & 7;    // float4 slot along BK
    const int row = tid >> 3;   // 0..31: token row / expert row for staging
    const int ty  = tid >> 4;   // 0..15 token quad
    const int tx  = tid & 15;   // 0..15 expert quad
    const size_t tokBase = (size_t)blockIdx.x * BM;
    const int    kc      = blockIdx.y;
    const size_t kbase   = (size_t)kc * (size_t)kchunk;

    double accd[4][4];
    float  accf[4][4];
#pragma unroll
    for (int i = 0; i < 4; ++i)
#pragma unroll
        for (int j = 0; j < 4; ++j) { accd[i][j] = 0.0; accf[i][j] = 0.0f; }

    const int ntiles = kchunk / BK;

    // prefetch tile 0
    size_t koff = kbase + kq * 4;
    float4 xa = *(const float4*)(x + (tokBase + row) * DMODEL + koff);
    float4 xb = *(const float4*)(x + (tokBase + row + 32) * DMODEL + koff);
    float4 wa = *(const float4*)(W + (size_t)row * DMODEL + koff);
    float4 wb = *(const float4*)(W + (size_t)(row + 32) * DMODEL + koff);

    for (int t = 0; t < ntiles; ++t) {
        __syncthreads();   // previous tile's readers done before overwrite
        *(float4*)(&xs[row     ][kq * 4]) = xa;   // ds_write_b128
        *(float4*)(&xs[row + 32][kq * 4]) = xb;
        *(float4*)(&ws[row     ][kq * 4]) = wa;
        *(float4*)(&ws[row + 32][kq * 4]) = wb;
        __syncthreads();

        if (t + 1 < ntiles) {   // issue next tile's loads BEFORE compute:
            koff = kbase + (size_t)(t + 1) * BK + kq * 4;
            xa = *(const float4*)(x + (tokBase + row) * DMODEL + koff);
            xb = *(const float4*)(x + (tokBase + row + 32) * DMODEL + koff);
            wa = *(const float4*)(W + (size_t)row * DMODEL + koff);
            wb = *(const float4*)(W + (size_t)(row + 32) * DMODEL + koff);
        }

#pragma unroll
        for (int g = 0; g < BK / 4; ++g) {   // 4 k-steps per group
            float a[16], b[16];
#pragma unroll
            for (int i = 0; i < 4; ++i)
                *(float4*)(&a[i * 4]) = *(const float4*)(&xs[ty * 4 + i][g * 4]);
#pragma unroll
            for (int j = 0; j < 4; ++j)
                *(float4*)(&b[j * 4]) = *(const float4*)(&ws[tx * 4 + j][g * 4]);
#pragma unroll
            for (int c = 0; c < 4; ++c)
#pragma unroll
                for (int i = 0; i < 4; ++i)
#pragma unroll
                    for (int j = 0; j < 4; ++j)
                        accf[i][j] = fmaf(a[i * 4 + c], b[j * 4 + c], accf[i][j]);
            if ((g & 3) == 3) {   // flush 16-k fp32 chunk into fp64
#pragma unroll
                for (int i = 0; i < 4; ++i)
#pragma unroll
                    for (int j = 0; j < 4; ++j) {
                        accd[i][j] += (double)accf[i][j];
                        accf[i][j] = 0.0f;
                    }
            }
        }
    }

#pragma unroll
    for (int i = 0; i < 4; ++i) {
        const size_t tok = tokBase + ty * 4 + i;
        float4 o;
        o.x = (float)accd[i][0]; o.y = (float)accd[i][1];
        o.z = (float)accd[i][2]; o.w = (float)accd[i][3];
        *(float4*)(part + ((size_t)kc * TOKENS + tok) * NEXP + tx * 4) = o;
    }
}

// Kernel 2: wave-per-token fused split-K reduce (fp64) + bias + top-8 + sigmoid.
// Lane e holds logit of expert e; comparisons on the fp32-CAST logit (that is
// what numpy sorts), ties broken toward lower index (lax.top_k stable order).
__global__ __launch_bounds__(256) void router_reduce_topk(
    const float* __restrict__ part, const float* __restrict__ bias,
    float* __restrict__ out_w, float* __restrict__ out_i, int ksplit)
{
    const int lane = threadIdx.x & 63;
    const int wid  = threadIdx.x >> 6;
    const size_t t = (size_t)blockIdx.x * 4 + wid;

    double vd = (double)bias[lane];
    for (int kc = 0; kc < ksplit; ++kc)
        vd += (double)part[((size_t)kc * TOKENS + t) * NEXP + lane];
    float v = (float)vd;

    const int myi = lane;
    float bv = 0.0f; int bi = 0;
#pragma unroll
    for (int r = 0; r < TOPK; ++r) {
        float mv = v; int mi = myi;
#pragma unroll
        for (int off = 32; off > 0; off >>= 1) {
            const float ov = __shfl_xor(mv, off, 64);
            const int   oi = __shfl_xor(mi, off, 64);
            if (ov > mv || (ov == mv && oi < mi)) { mv = ov; mi = oi; }
        }
        if (lane == r)  { bv = mv; bi = mi; }  // lane r keeps rank-r result
        if (myi == mi)  { v = -INFINITY; }     // remove winner (mi is uniform)
    }

    if (lane < TOPK) {
        out_w[t * TOPK + lane] = 1.0f / (1.0f + expf(-bv));
        out_i[t * TOPK + lane] = (float)bi;
    }
}

extern "C" void kernel_launch(void* const* d_in, const int* in_sizes, int n_in,
                              void* d_out, int out_size, void* d_ws, size_t ws_size,
                              hipStream_t stream) {
    const float* x    = (const float*)d_in[0];   // [4,4096,2048]
    const float* W    = (const float*)d_in[1];   // [64,2048]
    const float* bias = (const float*)d_in[2];   // [64]
    float* out_w = (float*)d_out;                          // [16384,8]
    float* out_i = (float*)d_out + (size_t)TOKENS * TOPK;  // [16384,8] as float
    float* part  = (float*)d_ws;                 // [ksplit,16384,64] fp32

    const size_t per = (size_t)TOKENS * NEXP * sizeof(float);
    int ksplit = 8;                      // 2048 blocks keeps all CUs fed
    while (ksplit > 1 && ws_size < (size_t)ksplit * per) ksplit >>= 1;
    const int kchunk = DMODEL / ksplit;

    dim3 grid(TOKENS / BM, ksplit);
    router_gemm<<<grid, 256, 0, stream>>>(x, W, part, kchunk);
    router_reduce_topk<<<TOKENS / 4, 256, 0, stream>>>(part, bias, out_w, out_i, ksplit);
}

// Round 5
// 279.694 us; speedup vs baseline: 1.0183x; 1.0183x over previous
//
#include <hip/hip_runtime.h>
#include <math.h>

#define TOKENS 16384
#define DMODEL 2048
#define NEXP   64
#define TOPK   8
#define BM     64
#define BK     32
#define WPAD   4   // wsT row stride 68 floats: R3-proven conflict-free b128 reads

// Kernel 1: partial logits. part[kc][t][e] = sum_{k in chunk kc} x[t][k]*W[e][k]
// Structure: only W goes through LDS (column-major wsT[k][expert], stride 68 —
// read pattern measured conflict-free in R3). x is read DIRECTLY from global:
// within a wave the 16 lanes sharing ty read identical addresses (broadcast,
// 4 cachelines/instr), L1-resident after first touch; addresses are
// base+immediate so the k-loop carries no x address VALU. W for tile t+1 is
// prefetched into registers (+8 VGPR) while tile t computes.
// fp32 FMA flushed to fp64 once per 32-k tile: total rounding ~1.4e-7, same
// order as numpy's own pairwise error -> top-k index stability preserved.
// R4 lessons encoded: no row-major LDS (8-way B-read conflicts), keep VGPR
// comfortably under 128 (and never force waves/EU via launch_bounds: R2
// spilled 430 MB).
__global__ __launch_bounds__(256) void router_gemm(
    const float* __restrict__ x, const float* __restrict__ W,
    float* __restrict__ part, int kchunk)
{
    __shared__ float wsT[BK][NEXP + WPAD];  // wsT[k][expert]

    const int tid = threadIdx.x;
    const int kq  = tid & 7;    // float4 slot along BK (W staging)
    const int row = tid >> 3;   // 0..31: expert row (W staging)
    const int ty  = tid >> 4;   // 0..15 token quad
    const int tx  = tid & 15;   // 0..15 expert quad
    const size_t tokBase = (size_t)blockIdx.x * BM;
    const int    kc      = blockIdx.y;
    const size_t kbase   = (size_t)kc * (size_t)kchunk;

    // per-thread x row pointers (4 token rows, broadcast across 16 lanes)
    const float* xr0 = x + (tokBase + ty * 4 + 0) * DMODEL + kbase;
    const float* xr1 = x + (tokBase + ty * 4 + 1) * DMODEL + kbase;
    const float* xr2 = x + (tokBase + ty * 4 + 2) * DMODEL + kbase;
    const float* xr3 = x + (tokBase + ty * 4 + 3) * DMODEL + kbase;

    double accd[4][4];
    float  accf[4][4];
#pragma unroll
    for (int i = 0; i < 4; ++i)
#pragma unroll
        for (int j = 0; j < 4; ++j) { accd[i][j] = 0.0; accf[i][j] = 0.0f; }

    const int ntiles = kchunk / BK;

    // prefetch W tile 0
    const float* wp = W + (size_t)row * DMODEL + kbase + kq * 4;
    float4 wa = *(const float4*)(wp);
    float4 wb = *(const float4*)(wp + (size_t)32 * DMODEL);

    for (int t = 0; t < ntiles; ++t) {
        __syncthreads();   // previous tile's B-readers done before overwrite
        wsT[kq * 4 + 0][row] = wa.x; wsT[kq * 4 + 1][row] = wa.y;
        wsT[kq * 4 + 2][row] = wa.z; wsT[kq * 4 + 3][row] = wa.w;
        wsT[kq * 4 + 0][row + 32] = wb.x; wsT[kq * 4 + 1][row + 32] = wb.y;
        wsT[kq * 4 + 2][row + 32] = wb.z; wsT[kq * 4 + 3][row + 32] = wb.w;
        __syncthreads();

        if (t + 1 < ntiles) {   // W prefetch overlaps this tile's compute
            wp += BK;
            wa = *(const float4*)(wp);
            wb = *(const float4*)(wp + (size_t)32 * DMODEL);
        }

        const int kb = t * BK;
#pragma unroll
        for (int g = 0; g < BK / 4; ++g) {   // 4 k-steps per group
            float4 xv0 = *(const float4*)(xr0 + kb + g * 4);
            float4 xv1 = *(const float4*)(xr1 + kb + g * 4);
            float4 xv2 = *(const float4*)(xr2 + kb + g * 4);
            float4 xv3 = *(const float4*)(xr3 + kb + g * 4);
            float4 b0 = *(const float4*)(&wsT[g * 4 + 0][tx * 4]);  // b128
            float4 b1 = *(const float4*)(&wsT[g * 4 + 1][tx * 4]);
            float4 b2 = *(const float4*)(&wsT[g * 4 + 2][tx * 4]);
            float4 b3 = *(const float4*)(&wsT[g * 4 + 3][tx * 4]);
            const float a[4][4] = {{xv0.x, xv0.y, xv0.z, xv0.w},
                                   {xv1.x, xv1.y, xv1.z, xv1.w},
                                   {xv2.x, xv2.y, xv2.z, xv2.w},
                                   {xv3.x, xv3.y, xv3.z, xv3.w}};
            const float b[4][4] = {{b0.x, b0.y, b0.z, b0.w},
                                   {b1.x, b1.y, b1.z, b1.w},
                                   {b2.x, b2.y, b2.z, b2.w},
                                   {b3.x, b3.y, b3.z, b3.w}};
#pragma unroll
            for (int c = 0; c < 4; ++c)
#pragma unroll
                for (int i = 0; i < 4; ++i)
#pragma unroll
                    for (int j = 0; j < 4; ++j)
                        accf[i][j] = fmaf(a[i][c], b[c][j], accf[i][j]);
        }
        // flush 32-k fp32 chunk into fp64 (once per tile)
#pragma unroll
        for (int i = 0; i < 4; ++i)
#pragma unroll
            for (int j = 0; j < 4; ++j) {
                accd[i][j] += (double)accf[i][j];
                accf[i][j] = 0.0f;
            }
    }

#pragma unroll
    for (int i = 0; i < 4; ++i) {
        const size_t tok = tokBase + ty * 4 + i;
        float4 o;
        o.x = (float)accd[i][0]; o.y = (float)accd[i][1];
        o.z = (float)accd[i][2]; o.w = (float)accd[i][3];
        *(float4*)(part + ((size_t)kc * TOKENS + tok) * NEXP + tx * 4) = o;
    }
}

// Kernel 2: wave-per-token fused split-K reduce (fp64) + bias + top-8 + sigmoid.
// Lane e holds logit of expert e; comparisons on the fp32-CAST logit (that is
// what numpy sorts), ties broken toward lower index (lax.top_k stable order).
__global__ __launch_bounds__(256) void router_reduce_topk(
    const float* __restrict__ part, const float* __restrict__ bias,
    float* __restrict__ out_w, float* __restrict__ out_i, int ksplit)
{
    const int lane = threadIdx.x & 63;
    const int wid  = threadIdx.x >> 6;
    const size_t t = (size_t)blockIdx.x * 4 + wid;

    double vd = (double)bias[lane];
    for (int kc = 0; kc < ksplit; ++kc)
        vd += (double)part[((size_t)kc * TOKENS + t) * NEXP + lane];
    float v = (float)vd;

    const int myi = lane;
    float bv = 0.0f; int bi = 0;
#pragma unroll
    for (int r = 0; r < TOPK; ++r) {
        float mv = v; int mi = myi;
#pragma unroll
        for (int off = 32; off > 0; off >>= 1) {
            const float ov = __shfl_xor(mv, off, 64);
            const int   oi = __shfl_xor(mi, off, 64);
            if (ov > mv || (ov == mv && oi < mi)) { mv = ov; mi = oi; }
        }
        if (lane == r)  { bv = mv; bi = mi; }  // lane r keeps rank-r result
        if (myi == mi)  { v = -INFINITY; }     // remove winner (mi is uniform)
    }

    if (lane < TOPK) {
        out_w[t * TOPK + lane] = 1.0f / (1.0f + expf(-bv));
        out_i[t * TOPK + lane] = (float)bi;
    }
}

extern "C" void kernel_launch(void* const* d_in, const int* in_sizes, int n_in,
                              void* d_out, int out_size, void* d_ws, size_t ws_size,
                              hipStream_t stream) {
    const float* x    = (const float*)d_in[0];   // [4,4096,2048]
    const float* W    = (const float*)d_in[1];   // [64,2048]
    const float* bias = (const float*)d_in[2];   // [64]
    float* out_w = (float*)d_out;                          // [16384,8]
    float* out_i = (float*)d_out + (size_t)TOKENS * TOPK;  // [16384,8] as float
    float* part  = (float*)d_ws;                 // [ksplit,16384,64] fp32

    const size_t per = (size_t)TOKENS * NEXP * sizeof(float);
    int ksplit = 8;                      // 2048 blocks keeps all CUs fed
    while (ksplit > 1 && ws_size < (size_t)ksplit * per) ksplit >>= 1;
    const int kchunk = DMODEL / ksplit;

    dim3 grid(TOKENS / BM, ksplit);
    router_gemm<<<grid, 256, 0, stream>>>(x, W, part, kchunk);
    router_reduce_topk<<<TOKENS / 4, 256, 0, stream>>>(part, bias, out_w, out_i, ksplit);
}

// Round 6
// 228.829 us; speedup vs baseline: 1.2447x; 1.2223x over previous
//
#include <hip/hip_runtime.h>
#include <math.h>

#define TOKENS 16384
#define DMODEL 2048
#define NEXP   64
#define TOPK   8
#define BM     64
#define BK     32
#define PAD    4   // column-major stride 68: b128 reads conflict-free (R3-measured)

// Kernel 1: partial logits. part[kc][t][e] = sum_{k in chunk kc} x[t][k]*W[e][k]
// R3's layout + R4's software pipelining:
//  - LDS tiles column-major xsT[k][token], wsT[k][expert], stride 68 (b128
//    fragment reads measured conflict-free in R3; a-reads are 16-lane
//    broadcasts, free).
//  - Tile t+1's global loads are issued BEFORE tile t's compute, so the
//    vmcnt wait (inside the LDS-write of the next iteration) lands after
//    ~1250 cycles of FMA instead of exposing ~900 cy HBM latency per tile
//    (R3's stall; R5 proved per-group direct-global loads are worse).
//  - fp32 FMA flushed to fp64 once per 32-k tile (~1.4e-7 total rounding,
//    numpy-grade top-k ordering).
// Tripwires from history: no forced waves/EU (R2: 430 MB spill), no
// row-major LDS (R4: 8-way conflicts), no inner-loop global loads (R5).
__global__ __launch_bounds__(256) void router_gemm(
    const float* __restrict__ x, const float* __restrict__ W,
    float* __restrict__ part, int kchunk)
{
    __shared__ float xsT[BK][BM + PAD];    // xsT[k][token]
    __shared__ float wsT[BK][NEXP + PAD];  // wsT[k][expert]

    const int tid = threadIdx.x;
    const int kq  = tid & 7;    // float4 slot along BK (staging)
    const int row = tid >> 3;   // 0..31: token/expert row (staging)
    const int ty  = tid >> 4;   // 0..15 token quad
    const int tx  = tid & 15;   // 0..15 expert quad
    const size_t tokBase = (size_t)blockIdx.x * BM;
    const int    kc      = blockIdx.y;
    const size_t kbase   = (size_t)kc * (size_t)kchunk;

    double accd[4][4];
    float  accf[4][4];
#pragma unroll
    for (int i = 0; i < 4; ++i)
#pragma unroll
        for (int j = 0; j < 4; ++j) { accd[i][j] = 0.0; accf[i][j] = 0.0f; }

    const int ntiles = kchunk / BK;

    // staging pointers, advanced by BK each tile
    const float* xp = x + (tokBase + row) * DMODEL + kbase + kq * 4;
    const float* wp = W + (size_t)row * DMODEL + kbase + kq * 4;

    // prefetch tile 0
    float4 xa = *(const float4*)(xp);
    float4 xb = *(const float4*)(xp + (size_t)32 * DMODEL);
    float4 wa = *(const float4*)(wp);
    float4 wb = *(const float4*)(wp + (size_t)32 * DMODEL);

    for (int t = 0; t < ntiles; ++t) {
        __syncthreads();   // previous tile's readers done before overwrite
        xsT[kq * 4 + 0][row] = xa.x; xsT[kq * 4 + 1][row] = xa.y;
        xsT[kq * 4 + 2][row] = xa.z; xsT[kq * 4 + 3][row] = xa.w;
        xsT[kq * 4 + 0][row + 32] = xb.x; xsT[kq * 4 + 1][row + 32] = xb.y;
        xsT[kq * 4 + 2][row + 32] = xb.z; xsT[kq * 4 + 3][row + 32] = xb.w;
        wsT[kq * 4 + 0][row] = wa.x; wsT[kq * 4 + 1][row] = wa.y;
        wsT[kq * 4 + 2][row] = wa.z; wsT[kq * 4 + 3][row] = wa.w;
        wsT[kq * 4 + 0][row + 32] = wb.x; wsT[kq * 4 + 1][row + 32] = wb.y;
        wsT[kq * 4 + 2][row + 32] = wb.z; wsT[kq * 4 + 3][row + 32] = wb.w;
        __syncthreads();

        if (t + 1 < ntiles) {   // issue next tile's loads; consumed next iter
            xp += BK; wp += BK;
            xa = *(const float4*)(xp);
            xb = *(const float4*)(xp + (size_t)32 * DMODEL);
            wa = *(const float4*)(wp);
            wb = *(const float4*)(wp + (size_t)32 * DMODEL);
        }

#pragma unroll
        for (int kk = 0; kk < BK; ++kk) {
            const float4 a = *(const float4*)(&xsT[kk][ty * 4]);  // broadcast
            const float4 b = *(const float4*)(&wsT[kk][tx * 4]);  // b128, free
            const float av[4] = {a.x, a.y, a.z, a.w};
            const float bv[4] = {b.x, b.y, b.z, b.w};
#pragma unroll
            for (int i = 0; i < 4; ++i)
#pragma unroll
                for (int j = 0; j < 4; ++j)
                    accf[i][j] = fmaf(av[i], bv[j], accf[i][j]);
        }
        // flush 32-k fp32 chunk into fp64 (once per tile)
#pragma unroll
        for (int i = 0; i < 4; ++i)
#pragma unroll
            for (int j = 0; j < 4; ++j) {
                accd[i][j] += (double)accf[i][j];
                accf[i][j] = 0.0f;
            }
    }

#pragma unroll
    for (int i = 0; i < 4; ++i) {
        const size_t tok = tokBase + ty * 4 + i;
        float4 o;
        o.x = (float)accd[i][0]; o.y = (float)accd[i][1];
        o.z = (float)accd[i][2]; o.w = (float)accd[i][3];
        *(float4*)(part + ((size_t)kc * TOKENS + tok) * NEXP + tx * 4) = o;
    }
}

// Kernel 2: wave-per-token fused split-K reduce (fp64) + bias + top-8 + sigmoid.
// Lane e holds logit of expert e; comparisons on the fp32-CAST logit (that is
// what numpy sorts), ties broken toward lower index (lax.top_k stable order).
__global__ __launch_bounds__(256) void router_reduce_topk(
    const float* __restrict__ part, const float* __restrict__ bias,
    float* __restrict__ out_w, float* __restrict__ out_i, int ksplit)
{
    const int lane = threadIdx.x & 63;
    const int wid  = threadIdx.x >> 6;
    const size_t t = (size_t)blockIdx.x * 4 + wid;

    double vd = (double)bias[lane];
    for (int kc = 0; kc < ksplit; ++kc)
        vd += (double)part[((size_t)kc * TOKENS + t) * NEXP + lane];
    float v = (float)vd;

    const int myi = lane;
    float bv = 0.0f; int bi = 0;
#pragma unroll
    for (int r = 0; r < TOPK; ++r) {
        float mv = v; int mi = myi;
#pragma unroll
        for (int off = 32; off > 0; off >>= 1) {
            const float ov = __shfl_xor(mv, off, 64);
            const int   oi = __shfl_xor(mi, off, 64);
            if (ov > mv || (ov == mv && oi < mi)) { mv = ov; mi = oi; }
        }
        if (lane == r)  { bv = mv; bi = mi; }  // lane r keeps rank-r result
        if (myi == mi)  { v = -INFINITY; }     // remove winner (mi is uniform)
    }

    if (lane < TOPK) {
        out_w[t * TOPK + lane] = 1.0f / (1.0f + expf(-bv));
        out_i[t * TOPK + lane] = (float)bi;
    }
}

extern "C" void kernel_launch(void* const* d_in, const int* in_sizes, int n_in,
                              void* d_out, int out_size, void* d_ws, size_t ws_size,
                              hipStream_t stream) {
    const float* x    = (const float*)d_in[0];   // [4,4096,2048]
    const float* W    = (const float*)d_in[1];   // [64,2048]
    const float* bias = (const float*)d_in[2];   // [64]
    float* out_w = (float*)d_out;                          // [16384,8]
    float* out_i = (float*)d_out + (size_t)TOKENS * TOPK;  // [16384,8] as float
    float* part  = (float*)d_ws;                 // [ksplit,16384,64] fp32

    const size_t per = (size_t)TOKENS * NEXP * sizeof(float);
    int ksplit = 8;                      // 2048 blocks keeps all CUs fed
    while (ksplit > 1 && ws_size < (size_t)ksplit * per) ksplit >>= 1;
    const int kchunk = DMODEL / ksplit;

    dim3 grid(TOKENS / BM, ksplit);
    router_gemm<<<grid, 256, 0, stream>>>(x, W, part, kchunk);
    router_reduce_topk<<<TOKENS / 4, 256, 0, stream>>>(part, bias, out_w, out_i, ksplit);
}